// Round 8
// baseline (387.315 us; speedup 1.0000x reference)
//
#include <hip/hip_runtime.h>
#include <math.h>

#define BN_ 8
#define CIN 256
#define COUT 256
#define HH 64
#define WW 64
#define HW 4096
#define KK 9
#define OC 18
#define EPS 1e-5f
#define NTOT (BN_ * COUT * HW)

// ws layout (float units):
//   off_ws: [B][18][HW]                 = 589824 floats
//   wTb:    bf16 [72][4][256][8] shorts = 294912 floats (main GEMM A image)
//   wob:    bf16 [72][4][32][8] shorts  = 36864 floats  (offset-conv A image)
//   stats:  [2][COUT]                   = 512 floats
//   xt:     bf16 [B][HW][256] shorts    = 4194304 floats (channel-last x)
#define OFF_WS 0
#define WTB_WS 589824
#define WOB_WS 884736
#define ST_WS  921600
#define XT_WS  922112

typedef float f32x4 __attribute__((ext_vector_type(4)));
typedef short s16x8 __attribute__((ext_vector_type(8)));

__device__ __forceinline__ unsigned short f2bf(float f) {
  unsigned int u = __float_as_uint(f);
  unsigned int r = (u + 0x7fffu + ((u >> 16) & 1u)) >> 16;  // RNE
  return (unsigned short)r;
}
__device__ __forceinline__ float bf2f(short s) {
  return __uint_as_float(((unsigned int)(unsigned short)s) << 16);
}

// ---------------- Kernel W1: pack w_off -> bf16 fragment image (M=32 pad) ----------------
__global__ __launch_bounds__(256) void wob_kernel(
    const float* __restrict__ w_off, unsigned short* __restrict__ wob) {
  const int ki = blockIdx.x;          // 0..71
  const int kk = ki >> 3;
  const int cc0 = (ki & 7) << 5;
#pragma unroll
  for (int r = 0; r < 4; ++r) {
    int e = r * 256 + threadIdx.x;    // g*256 + m*8 + j
    int g = e >> 8, m = (e >> 3) & 31, j = e & 7;
    int c = cc0 + g * 8 + j;
    unsigned short v = 0;
    if (m < OC) v = f2bf(w_off[((size_t)m * CIN + c) * 9 + kk]);
    wob[(size_t)ki * 1024 + e] = v;
  }
}

// ---------------- Kernel A: offset conv as MFMA GEMM + xt emission ----------------
// grid (HH, B). Also writes xt[b][h*64+w][c] (channel-last bf16 x) from the staged
// middle halo row -- replaces the former standalone xpose kernel (x read once).
__global__ __launch_bounds__(256) void offset_kernel(
    const float* __restrict__ x, const unsigned short* __restrict__ wob,
    const float* __restrict__ b_off, float* __restrict__ off_ws,
    unsigned short* __restrict__ xt) {
  __shared__ __align__(16) char smem[32768];
  __shared__ float s_x[64][3][72];
  const int t = threadIdx.x;
  const int lane = t & 63;
  const int wv = t >> 6;
  const int b = blockIdx.x & 7;
  const int h = blockIdx.x >> 3;
  const float* xb = x + (size_t)b * CIN * HW;
  const int fr = lane & 15, fq = lane >> 4;
  unsigned short* sb = (unsigned short*)smem + wv * 2048;
  float* red = (float*)smem;

  f32x4 acc[2][4] = {};

  // ---- stage x rows + emit xt + run MFMA-GEMM over 4 c-chunks of 64 ----
  for (int c0 = 0; c0 < CIN; c0 += 64) {
    __syncthreads();
    const int rowlane = t >> 4;
    const int l16 = t & 15;
#pragma unroll
    for (int it = 0; it < 12; ++it) {
      int rid = it * 16 + rowlane;           // 0..191
      int c = rid / 3, r = rid - 3 * (rid / 3);
      int hh = h + r - 1;
      float4 v = make_float4(0.f, 0.f, 0.f, 0.f);
      if (hh >= 0 && hh < HH)
        v = *(const float4*)(xb + (size_t)(c0 + c) * HW + hh * WW + l16 * 4);
      *(float4*)&s_x[c][r][4 + l16 * 4] = v;
    }
    __syncthreads();

    // emit xt for this (b, h, c-chunk) from the middle row
    {
      unsigned short* xo = xt + ((size_t)b * HW + h * WW) * 256 + c0;
#pragma unroll
      for (int r = 0; r < 2; ++r) {
        int e = r * 256 + t;                 // 0..511 = wpx*8 + s
        int wpx = e >> 3, s = e & 7;
        s16x8 v;
#pragma unroll
        for (int j = 0; j < 8; ++j) v[j] = (short)f2bf(s_x[s * 8 + j][1][4 + wpx]);
        *(s16x8*)(xo + (size_t)wpx * 256 + s * 8) = v;
      }
    }

    // im2col B-tiles + MFMA: wave wv owns k-iters (c-chunk, kk half)
    // per c0 chunk: 2 sub-chunks of 32 ch x ... total ki space = kk*8 + cstep.
    // Keep prior K-split: wave handles ki = wv*18 + s; gate to ki in this c-chunk.
#pragma unroll
    for (int s = 0; s < 18; ++s) {
      const int ki = wv * 18 + s;
      const int cstep = ki & 7;
      if ((cstep >> 1) != (c0 >> 6)) continue;   // this wave-iter uses chunk c0
      const int kk = ki >> 3;
      const int cc = (cstep & 1) * 32;           // 0 or 32 within chunk
      const int ky = kk / 3 - 1, kx = kk % 3 - 1;
      const int r = ky + 1;
      const int xcol = lane + kx;
      const bool ok = (xcol >= 0) && (xcol < WW);

      s16x8 af[2];
      const unsigned short* ap = wob + (size_t)ki * 1024;
#pragma unroll
      for (int i = 0; i < 2; ++i)
        af[i] = *(const s16x8*)&ap[(fq * 32 + i * 16 + fr) * 8];

#pragma unroll
      for (int g = 0; g < 4; ++g) {
        s16x8 v;
#pragma unroll
        for (int j = 0; j < 8; ++j) {
          float val = ok ? s_x[cc + g * 8 + j][r][4 + xcol] : 0.f;
          v[j] = (short)f2bf(val);
        }
        *(s16x8*)&sb[(g * 64 + lane) * 8] = v;
      }
      __builtin_amdgcn_s_waitcnt(0);

      s16x8 bf[4];
#pragma unroll
      for (int jn = 0; jn < 4; ++jn)
        bf[jn] = *(const s16x8*)&sb[(fq * 64 + jn * 16 + fr) * 8];
#pragma unroll
      for (int i = 0; i < 2; ++i)
#pragma unroll
        for (int jn = 0; jn < 4; ++jn)
          acc[i][jn] = __builtin_amdgcn_mfma_f32_16x16x32_bf16(af[i], bf[jn], acc[i][jn], 0, 0, 0);
    }
  }

  // ---- cross-wave K reduction via LDS ----
  __syncthreads();
#pragma unroll
  for (int i = 0; i < 2; ++i)
#pragma unroll
    for (int jn = 0; jn < 4; ++jn)
#pragma unroll
      for (int rg = 0; rg < 4; ++rg)
        red[wv * 2048 + (i * 16 + fq * 4 + rg) * 64 + jn * 16 + fr] = acc[i][jn][rg];
  __syncthreads();

  const int m = t >> 3;
  const int pq = (t & 7) * 8;
  float4 v0 = make_float4(0.f, 0.f, 0.f, 0.f), v1 = v0;
#pragma unroll
  for (int w = 0; w < 4; ++w) {
    float4 a = *(float4*)&red[w * 2048 + m * 64 + pq];
    float4 c = *(float4*)&red[w * 2048 + m * 64 + pq + 4];
    v0.x += a.x; v0.y += a.y; v0.z += a.z; v0.w += a.w;
    v1.x += c.x; v1.y += c.y; v1.z += c.z; v1.w += c.w;
  }
  if (m < OC) {
    float bo = b_off[m];
    v0.x += bo; v0.y += bo; v0.z += bo; v0.w += bo;
    v1.x += bo; v1.y += bo; v1.z += bo; v1.w += bo;
    float* op = off_ws + ((size_t)b * OC + m) * HW + h * WW + pq;
    *(float4*)op = v0;
    *(float4*)(op + 4) = v1;
  }
}

// ---------------- Kernel W0: pack w -> bf16 k-major image ----------------
__global__ __launch_bounds__(256) void wtrans_kernel(
    const float* __restrict__ w, unsigned short* __restrict__ wTb) {
  const int kb = blockIdx.x;          // 0..71
  const int kk = kb >> 3;
  const int c0 = (kb & 7) << 5;
  const int o = threadIdx.x;
#pragma unroll
  for (int g = 0; g < 4; ++g)
#pragma unroll
    for (int j = 0; j < 8; ++j) {
      int c = c0 + g * 8 + j;
      wTb[(((size_t)kb * 4 + g) * 256 + o) * 8 + j] =
          f2bf(w[((size_t)o * CIN + c) * 9 + kk]);
    }
}

// ---------------- Kernel B: wave-specialized gather MFMA GEMM + fused stats --------
// grid 1024: b = bx&7 (XCD), pt = bx>>3 (32-px tile). Block 256 = 4 waves.
// Waves 0-1: bilinear gather (32px x 4oct = 128 lanes, no redundancy) -> s_b.
// Waves 2-3: A staging via global_load_lds. All waves: 64o x 32px MFMA.
// LDS 36KB -> 4 blocks/CU: barrier drains of one block overlap 3 others' compute.
__global__ __launch_bounds__(256, 4) void gemm_kernel(
    const unsigned short* __restrict__ xt, const unsigned short* __restrict__ wTb,
    const float* __restrict__ off_ws, const float* __restrict__ bias,
    float* __restrict__ out, float* __restrict__ stats) {
  __shared__ unsigned short s_a[2][8192];   // [oct][o][8] bf16, 16KB each
  __shared__ unsigned short s_b[2][1024];   // [oct][px][8] bf16,  2KB each
  const int t = threadIdx.x;
  const int lane = t & 63;
  const int wv = t >> 6;
  const int b = blockIdx.x & 7;
  const int pt = blockIdx.x >> 3;
  const int p0 = pt * 32;
  const int fr = lane & 15, fq = lane >> 4;
  const unsigned short* xtb = xt + (size_t)b * HW * 256;

  // gather mapping (threads 0..127 = waves 0,1)
  const int gpx = t & 31;
  const int goct = (t >> 5) & 3;
  const int gp = p0 + gpx;
  const int gh = gp >> 6, gw = gp & 63;

  int cofs[4];
  float qw[4];
  auto comp_idx = [&](int kk) {
    float dy = off_ws[((size_t)b * OC + 2 * kk) * HW + gp];
    float dx = off_ws[((size_t)b * OC + 2 * kk + 1) * HW + gp];
    float py = (float)(kk / 3 - 1 + gh) + dy;
    float pxf = (float)(kk % 3 - 1 + gw) + dx;
    float y0f = floorf(py), x0f = floorf(pxf);
    float fy = py - y0f, fx = pxf - x0f;
    int y0 = (int)y0f, x0 = (int)x0f;
    int y1 = y0 + 1, x1 = x0 + 1;
    bool vy0 = (y0 >= 0) && (y0 < HH), vy1 = (y1 >= 0) && (y1 < HH);
    bool vx0 = (x0 >= 0) && (x0 < WW), vx1 = (x1 >= 0) && (x1 < WW);
    int cy0 = min(max(y0, 0), HH - 1), cy1 = min(max(y1, 0), HH - 1);
    int cx0 = min(max(x0, 0), WW - 1), cx1 = min(max(x1, 0), WW - 1);
    cofs[0] = (cy0 * WW + cx0) * 512;  qw[0] = (vy0 && vx0) ? (1.f - fy) * (1.f - fx) : 0.f;
    cofs[1] = (cy0 * WW + cx1) * 512;  qw[1] = (vy0 && vx1) ? (1.f - fy) * fx : 0.f;
    cofs[2] = (cy1 * WW + cx0) * 512;  qw[2] = (vy1 && vx0) ? fy * (1.f - fx) : 0.f;
    cofs[3] = (cy1 * WW + cx1) * 512;  qw[3] = (vy1 && vx1) ? fy * fx : 0.f;
  };

  s16x8 g[4];
  auto gather = [&](int c0) {
    const char* bp = (const char*)xtb + (size_t)(c0 + goct * 8) * 2;
#pragma unroll
    for (int k = 0; k < 4; ++k)
      __builtin_memcpy(&g[k], bp + cofs[k], 16);
  };

  auto combine_write = [&](int buf) {
    s16x8 v;
#pragma unroll
    for (int j = 0; j < 8; ++j) {
      float val = 0.f;
#pragma unroll
      for (int k = 0; k < 4; ++k)
        val = fmaf(qw[k], bf2f(g[k][j]), val);
      v[j] = (short)f2bf(val);
    }
    *(s16x8*)&s_b[buf][(goct * 32 + gpx) * 8] = v;
  };

  auto stage_a = [&](int iter, int buf) {   // waves 2,3 only
    const unsigned char* gb = (const unsigned char*)(wTb + (size_t)iter * 8192);
    unsigned char* lb = (unsigned char*)s_a[buf];
#pragma unroll
    for (int i = 0; i < 8; ++i) {
      int chunk = (((wv - 2) * 8) + i) * 1024;
      __builtin_amdgcn_global_load_lds(
          (const __attribute__((address_space(1))) unsigned char*)(gb + chunk + lane * 16),
          (__attribute__((address_space(3))) unsigned char*)(lb + chunk),
          16, 0, 0);
    }
  };

  f32x4 acc[4][2] = {};

  // prologue
  if (wv < 2) {
    comp_idx(0);
    gather(0);
    combine_write(0);
  } else {
    stage_a(0, 0);
  }
  __syncthreads();

  for (int iter = 0; iter < 72; ++iter) {
    const int cur = iter & 1;
    s16x8 af[4], bfr[2];
#pragma unroll
    for (int i = 0; i < 4; ++i)
      af[i] = *(const s16x8*)&s_a[cur][(fq * 256 + wv * 64 + i * 16 + fr) * 8];
#pragma unroll
    for (int j = 0; j < 2; ++j)
      bfr[j] = *(const s16x8*)&s_b[cur][(fq * 32 + j * 16 + fr) * 8];

    const int nxt = iter + 1;
    if (nxt < 72) {
      if (wv >= 2) {
        stage_a(nxt, cur ^ 1);
      } else {
        if ((nxt & 7) == 0) comp_idx(nxt >> 3);
        gather((nxt & 7) << 5);
      }
    }

#pragma unroll
    for (int i = 0; i < 4; ++i)
#pragma unroll
      for (int j = 0; j < 2; ++j)
        acc[i][j] = __builtin_amdgcn_mfma_f32_16x16x32_bf16(af[i], bfr[j], acc[i][j], 0, 0, 0);

    if (nxt < 72 && wv < 2) combine_write(cur ^ 1);
    __syncthreads();
  }

  // epilogue: + bias, store, fused per-channel sum/sumsq
#pragma unroll
  for (int i = 0; i < 4; ++i) {
#pragma unroll
    for (int rg = 0; rg < 4; ++rg) {
      int o = wv * 64 + i * 16 + fq * 4 + rg;
      float bv = bias[o];
      float* op = out + ((size_t)(b * COUT + o)) * HW + p0 + fr;
      float s = 0.f, s2 = 0.f;
#pragma unroll
      for (int j = 0; j < 2; ++j) {
        float val = acc[i][j][rg] + bv;
        op[j * 16] = val;
        s += val; s2 += val * val;
      }
#pragma unroll
      for (int m = 1; m < 16; m <<= 1) {
        s += __shfl_xor(s, m);
        s2 += __shfl_xor(s2, m);
      }
      if (fr == 0) {
        atomicAdd(&stats[o], s);
        atomicAdd(&stats[COUT + o], s2);
      }
    }
  }
}

// ---------------- Kernel D: normalize + ReLU in-place ----------------
__global__ __launch_bounds__(256) void bn_kernel(
    float* __restrict__ out, const float* __restrict__ stats,
    const float* __restrict__ gamma, const float* __restrict__ beta) {
  int i4 = (blockIdx.x * 256 + threadIdx.x) * 4;
  int o = (i4 >> 12) & (COUT - 1);
  const float inv_n = 1.f / (float)(BN_ * HW);
  float mean = stats[o] * inv_n;
  float var = stats[COUT + o] * inv_n - mean * mean;
  float sc = gamma[o] * rsqrtf(var + EPS);
  float sh = beta[o] - mean * sc;
  float4 v = *(float4*)(out + i4);
  v.x = fmaxf(fmaf(v.x, sc, sh), 0.f);
  v.y = fmaxf(fmaf(v.y, sc, sh), 0.f);
  v.z = fmaxf(fmaf(v.z, sc, sh), 0.f);
  v.w = fmaxf(fmaf(v.w, sc, sh), 0.f);
  *(float4*)(out + i4) = v;
}

extern "C" void kernel_launch(void* const* d_in, const int* in_sizes, int n_in,
                              void* d_out, int out_size, void* d_ws, size_t ws_size,
                              hipStream_t stream) {
  const float* x     = (const float*)d_in[0];
  const float* w_off = (const float*)d_in[1];
  const float* b_off = (const float*)d_in[2];
  const float* w     = (const float*)d_in[3];
  const float* bias  = (const float*)d_in[4];
  const float* gamma = (const float*)d_in[5];
  const float* beta  = (const float*)d_in[6];
  float* out = (float*)d_out;
  float* ws = (float*)d_ws;
  float* off_ws = ws + OFF_WS;
  unsigned short* wTb = (unsigned short*)(ws + WTB_WS);
  unsigned short* wob = (unsigned short*)(ws + WOB_WS);
  float* stats = ws + ST_WS;
  unsigned short* xt = (unsigned short*)(ws + XT_WS);

  hipMemsetAsync(stats, 0, 2 * COUT * sizeof(float), stream);
  wob_kernel<<<72, 256, 0, stream>>>(w_off, wob);
  wtrans_kernel<<<72, 256, 0, stream>>>(w, wTb);
  offset_kernel<<<512, 256, 0, stream>>>(x, wob, b_off, off_ws, xt);
  gemm_kernel<<<1024, 256, 0, stream>>>(xt, wTb, off_ws, bias, out, stats);
  bn_kernel<<<NTOT / 1024, 256, 0, stream>>>(out, stats, gamma, beta);
}